// Round 1
// baseline (286.302 us; speedup 1.0000x reference)
//
#include <hip/hip_runtime.h>
#include <math.h>

#define BB   4
#define KK   4
#define DD   192
#define HH   64
#define WW   64
#define LL   (HH*WW)          // 4096
#define NN   16
#define RR   6
#define PROJ (RR + 2*NN)      // 38
#define CH   32               // chunk length
#define NC   (LL/CH)          // 128 chunks

// ---------------------------------------------------------------------------
// Kernel 0: permute x[b,k,d,h,w] -> xs[b,k,l,d] (scan order per k), LDS tiled.
// l mappings: k0: l=h*W+w ; k1: l=w*H+(H-1-h) ; k2: l=L-1-(h*W+w) ; k3: l=(W-1-w)*H+h
// ---------------------------------------------------------------------------
#define TD  32
#define TSH 8
#define TSW 32
__global__ __launch_bounds__(256) void k_transpose(const float* __restrict__ x,
                                                   float* __restrict__ xs) {
    int bid = blockIdx.x;
    const int nw = WW / TSW, nh = HH / TSH, nd = DD / TD;
    int wblk = bid % nw; bid /= nw;
    int hblk = bid % nh; bid /= nh;
    int dblk = bid % nd; bid /= nd;
    int bk = bid;                  // 0..15
    int k = bk % KK;
    int d0 = dblk * TD, h0 = hblk * TSH, w0 = wblk * TSW;
    const int SP = TSH * TSW + 1;  // 257: pad so d-strided reads are conflict-free
    __shared__ float tile[TD * (TSH * TSW + 1)];
    int tid = threadIdx.x;
    const float* xp = x + (size_t)bk * DD * LL;
    #pragma unroll
    for (int it = 0; it < (TD * TSH * TSW) / 256; ++it) {
        int idx = it * 256 + tid;
        int d = idx >> 8;          // 0..31
        int s = idx & 255;         // h*32+w
        int h = s >> 5, w = s & 31;
        tile[d * SP + s] = xp[(size_t)(d0 + d) * LL + (size_t)(h0 + h) * WW + (w0 + w)];
    }
    __syncthreads();
    float* xsp = xs + (size_t)bk * LL * DD;
    #pragma unroll
    for (int it = 0; it < (TD * TSH * TSW) / 256; ++it) {
        int idx = it * 256 + tid;
        int d = idx & 31;
        int s = idx >> 5;
        int h = s >> 5, w = s & 31;
        int hh_ = h0 + h, ww_ = w0 + w;
        int l;
        if      (k == 0) l = hh_ * WW + ww_;
        else if (k == 1) l = ww_ * HH + (HH - 1 - hh_);
        else if (k == 2) l = LL - 1 - (hh_ * WW + ww_);
        else             l = (WW - 1 - ww_) * HH + hh_;
        xsp[(size_t)l * DD + d0 + d] = tile[d * SP + s];
    }
}

// ---------------------------------------------------------------------------
// Kernel 1: projection x_dbl[b,k,r,l] = sum_d xs[b,k,l,d] * xpw[k,r,d]
// split into dt_low (r<6), Bs (6..21), Cs (22..37). Layouts all (b,k,l,·).
// ---------------------------------------------------------------------------
#define TL 32
__global__ __launch_bounds__(256) void k_proj(const float* __restrict__ xs,
                                              const float* __restrict__ xpw,
                                              float* __restrict__ dtl,
                                              float* __restrict__ Bsg,
                                              float* __restrict__ Csg) {
    int bid = blockIdx.x;
    int lblk = bid % (LL / TL);
    int bk   = bid / (LL / TL);
    int k = bk % KK;
    int l0 = lblk * TL;
    const int RS = DD + 4;          // 196 (keeps 16B alignment, breaks bank stride)
    __shared__ __align__(16) float xsb[TL * (DD + 4)];
    __shared__ __align__(16) float wb[PROJ * (DD + 4)];
    int tid = threadIdx.x;
    const float* xsp = xs + ((size_t)bk * LL + l0) * DD;
    for (int idx = tid; idx < TL * DD; idx += 256) {
        int l = idx / DD, d = idx % DD;
        xsb[l * RS + d] = xsp[idx];
    }
    const float* wp = xpw + (size_t)k * PROJ * DD;
    for (int idx = tid; idx < PROJ * DD; idx += 256) {
        int r = idx / DD, d = idx % DD;
        wb[r * RS + d] = wp[idx];
    }
    __syncthreads();
    for (int o = tid; o < TL * PROJ; o += 256) {
        int l = o / PROJ, r = o % PROJ;
        const float4* xa = (const float4*)(xsb + l * RS);
        const float4* wa = (const float4*)(wb + r * RS);
        float acc = 0.f;
        #pragma unroll 8
        for (int d4 = 0; d4 < DD / 4; ++d4) {
            float4 a = xa[d4], w = wa[d4];
            acc += a.x * w.x + a.y * w.y + a.z * w.z + a.w * w.w;
        }
        size_t base = (size_t)bk * LL + (l0 + l);
        if      (r < RR)        dtl[base * RR + r] = acc;
        else if (r < RR + NN)   Bsg[base * NN + (r - RR)] = acc;
        else                    Csg[base * NN + (r - RR - NN)] = acc;
    }
}

__device__ __forceinline__ float softplus_f(float x) {
    float e = __expf(-fabsf(x));
    return fmaxf(x, 0.f) + __logf(1.f + e);
}

// ---------------------------------------------------------------------------
// Kernel 2 (pass 1): per-chunk local scan from h=0 -> S (final local state) and
// sum of dt over the chunk. thread = d channel. grid = (b*K) * NC.
// ---------------------------------------------------------------------------
__global__ __launch_bounds__(192) void k_scan1(const float* __restrict__ xs,
                                               const float* __restrict__ dtl,
                                               const float* __restrict__ Bsg,
                                               const float* __restrict__ dtw_g,
                                               const float* __restrict__ dtb_g,
                                               const float* __restrict__ A_log,
                                               float* __restrict__ Sbuf,
                                               float* __restrict__ sdbuf) {
    int bid = blockIdx.x;
    int c  = bid % NC;
    int bk = bid / NC;
    int k = bk % KK;
    int d = threadIdx.x;
    int l0 = c * CH;
    __shared__ float dts[CH * RR];
    __shared__ float Bsh[CH * NN];
    for (int idx = threadIdx.x; idx < CH * RR; idx += 192)
        dts[idx] = dtl[((size_t)bk * LL + l0) * RR + idx];
    for (int idx = threadIdx.x; idx < CH * NN; idx += 192)
        Bsh[idx] = Bsg[((size_t)bk * LL + l0) * NN + idx];
    __syncthreads();

    float w6[RR];
    #pragma unroll
    for (int r = 0; r < RR; ++r) w6[r] = dtw_g[((size_t)k * DD + d) * RR + r];
    float bias = dtb_g[k * DD + d];
    float Av[NN];
    #pragma unroll
    for (int n = 0; n < NN; ++n) Av[n] = -__expf(A_log[((size_t)k * DD + d) * NN + n]);
    float S[NN];
    #pragma unroll
    for (int n = 0; n < NN; ++n) S[n] = 0.f;
    float sumdt = 0.f;
    const float* up = xs + ((size_t)bk * LL + l0) * DD + d;
    for (int i = 0; i < CH; ++i) {
        float pre = bias;
        #pragma unroll
        for (int r = 0; r < RR; ++r) pre = fmaf(dts[i * RR + r], w6[r], pre);
        float dt = softplus_f(pre);
        float u = up[(size_t)i * DD];
        float dtu = dt * u;
        sumdt += dt;
        #pragma unroll
        for (int n = 0; n < NN; ++n) {
            float wn = __expf(dt * Av[n]);
            S[n] = fmaf(S[n], wn, dtu * Bsh[i * NN + n]);
        }
    }
    size_t base = (size_t)(bk * NC + c) * DD + d;
    float4* Sp = (float4*)(Sbuf + base * NN);
    #pragma unroll
    for (int q = 0; q < 4; ++q)
        Sp[q] = make_float4(S[4 * q], S[4 * q + 1], S[4 * q + 2], S[4 * q + 3]);
    sdbuf[base] = sumdt;
}

// ---------------------------------------------------------------------------
// Kernel 3 (pass 2): sequential scan over the NC chunk summaries.
// thread = (bk,d,n). Writes h_start IN PLACE over Sbuf (read-before-write).
// chunk product over states: prod_i exp(A_n*dt_i) = exp(A_n * sum dt_i).
// ---------------------------------------------------------------------------
__global__ __launch_bounds__(256) void k_scan2(float* __restrict__ SH,      // in: S, out: h_start
                                               const float* __restrict__ sdbuf,
                                               const float* __restrict__ A_log) {
    int tid = blockIdx.x * 256 + threadIdx.x;   // B*K*D*N = 49152
    int n  = tid & (NN - 1);
    int d  = (tid >> 4) % DD;
    int bk = tid / (NN * DD);
    int k = bk % KK;
    float A = -__expf(A_log[((size_t)k * DD + d) * NN + n]);
    float h = 0.f;
    for (int c = 0; c < NC; ++c) {
        size_t base = (size_t)(bk * NC + c) * DD + d;
        float Sc = SH[base * NN + n];
        SH[base * NN + n] = h;                  // h_start for chunk c
        h = fmaf(h, __expf(A * sdbuf[base]), Sc);
    }
}

// ---------------------------------------------------------------------------
// Kernel 4 (pass 3): replay chunk with true h_start, emit ys = y + Ds*u.
// Writes IN PLACE over xs (each thread reads u then overwrites same address).
// ---------------------------------------------------------------------------
__global__ __launch_bounds__(192) void k_scan3(float* __restrict__ xs,       // in: u, out: ys
                                               const float* __restrict__ dtl,
                                               const float* __restrict__ Bsg,
                                               const float* __restrict__ Csg,
                                               const float* __restrict__ dtw_g,
                                               const float* __restrict__ dtb_g,
                                               const float* __restrict__ A_log,
                                               const float* __restrict__ Dsg,
                                               const float* __restrict__ Hbuf) {
    int bid = blockIdx.x;
    int c  = bid % NC;
    int bk = bid / NC;
    int k = bk % KK;
    int d = threadIdx.x;
    int l0 = c * CH;
    __shared__ float dts[CH * RR];
    __shared__ float Bsh[CH * NN];
    __shared__ float Csh[CH * NN];
    for (int idx = threadIdx.x; idx < CH * RR; idx += 192)
        dts[idx] = dtl[((size_t)bk * LL + l0) * RR + idx];
    for (int idx = threadIdx.x; idx < CH * NN; idx += 192) {
        Bsh[idx] = Bsg[((size_t)bk * LL + l0) * NN + idx];
        Csh[idx] = Csg[((size_t)bk * LL + l0) * NN + idx];
    }
    __syncthreads();

    float w6[RR];
    #pragma unroll
    for (int r = 0; r < RR; ++r) w6[r] = dtw_g[((size_t)k * DD + d) * RR + r];
    float bias = dtb_g[k * DD + d];
    float Av[NN];
    #pragma unroll
    for (int n = 0; n < NN; ++n) Av[n] = -__expf(A_log[((size_t)k * DD + d) * NN + n]);
    float h[NN];
    const float4* Hp = (const float4*)(Hbuf + ((size_t)(bk * NC + c) * DD + d) * NN);
    #pragma unroll
    for (int q = 0; q < 4; ++q) {
        float4 t = Hp[q];
        h[4 * q] = t.x; h[4 * q + 1] = t.y; h[4 * q + 2] = t.z; h[4 * q + 3] = t.w;
    }
    float Dsd = Dsg[k * DD + d];
    float* up = xs + ((size_t)bk * LL + l0) * DD + d;
    for (int i = 0; i < CH; ++i) {
        float pre = bias;
        #pragma unroll
        for (int r = 0; r < RR; ++r) pre = fmaf(dts[i * RR + r], w6[r], pre);
        float dt = softplus_f(pre);
        float u = up[(size_t)i * DD];
        float dtu = dt * u;
        float y = 0.f;
        #pragma unroll
        for (int n = 0; n < NN; ++n) {
            float wn = __expf(dt * Av[n]);
            h[n] = fmaf(h[n], wn, dtu * Bsh[i * NN + n]);
            y = fmaf(h[n], Csh[i * NN + n], y);
        }
        up[(size_t)i * DD] = y + Dsd * u;
    }
}

// ---------------------------------------------------------------------------
// Kernel 5: cross_merge (sum over k with inverse scan maps) + LayerNorm over D.
// one wave (64 lanes) per spatial position; lane covers d, d+64, d+128.
// ---------------------------------------------------------------------------
__global__ __launch_bounds__(256) void k_merge_ln(const float* __restrict__ y,
                                                  const float* __restrict__ lnw,
                                                  const float* __restrict__ lnb,
                                                  float* __restrict__ out) {
    int wave = threadIdx.x >> 6;
    int lane = threadIdx.x & 63;
    int g = blockIdx.x * 4 + wave;        // 0 .. B*L-1
    int b = g / LL;
    int p = g % LL;
    int h = p / WW, w = p % WW;
    int lk0 = p;
    int lk1 = w * HH + (HH - 1 - h);
    int lk2 = LL - 1 - p;
    int lk3 = (WW - 1 - w) * HH + h;
    size_t base = (size_t)b * KK * LL;
    float v[3];
    #pragma unroll
    for (int i = 0; i < 3; ++i) {
        int d = lane + 64 * i;
        float acc;
        acc  = y[(base + 0 * LL + lk0) * DD + d];
        acc += y[(base + 1 * LL + lk1) * DD + d];
        acc += y[(base + 2 * LL + lk2) * DD + d];
        acc += y[(base + 3 * LL + lk3) * DD + d];
        v[i] = acc;
    }
    float s  = v[0] + v[1] + v[2];
    float sq = v[0] * v[0] + v[1] * v[1] + v[2] * v[2];
    #pragma unroll
    for (int off = 32; off >= 1; off >>= 1) {
        s  += __shfl_xor(s, off, 64);
        sq += __shfl_xor(sq, off, 64);
    }
    float mu  = s * (1.f / DD);
    float var = sq * (1.f / DD) - mu * mu;
    float rs  = rsqrtf(var + 1e-5f);
    #pragma unroll
    for (int i = 0; i < 3; ++i) {
        int d = lane + 64 * i;
        out[(size_t)g * DD + d] = (v[i] - mu) * rs * lnw[d] + lnb[d];
    }
}

// ---------------------------------------------------------------------------
extern "C" void kernel_launch(void* const* d_in, const int* in_sizes, int n_in,
                              void* d_out, int out_size, void* d_ws, size_t ws_size,
                              hipStream_t stream) {
    const float* x     = (const float*)d_in[0];
    const float* xpw   = (const float*)d_in[1];
    const float* dtw   = (const float*)d_in[2];
    const float* dtb   = (const float*)d_in[3];
    const float* A_log = (const float*)d_in[4];
    const float* Dsg   = (const float*)d_in[5];
    const float* lnw   = (const float*)d_in[6];
    const float* lnb   = (const float*)d_in[7];
    float* out = (float*)d_out;

    float* ws = (float*)d_ws;
    const size_t n_xs = (size_t)BB * KK * LL * DD;       // 12,582,912
    const size_t n_dtl = (size_t)BB * KK * LL * RR;      //    393,216
    const size_t n_bc  = (size_t)BB * KK * LL * NN;      //  1,048,576
    const size_t n_S   = (size_t)BB * KK * NC * DD * NN; //  6,291,456
    const size_t n_sd  = (size_t)BB * KK * NC * DD;      //    393,216
    float* xs   = ws;                    ws += n_xs;
    float* dtl  = ws;                    ws += n_dtl;
    float* Bsg  = ws;                    ws += n_bc;
    float* Csg  = ws;                    ws += n_bc;
    float* Sbuf = ws;                    ws += n_S;   // reused as h_start by k_scan2
    float* sd   = ws;                    ws += n_sd;
    // total: 21,757,952 floats = ~87 MB

    k_transpose<<<dim3((BB*KK) * (DD/TD) * (HH/TSH) * (WW/TSW)), dim3(256), 0, stream>>>(x, xs);
    k_proj<<<dim3((BB*KK) * (LL/TL)), dim3(256), 0, stream>>>(xs, xpw, dtl, Bsg, Csg);
    k_scan1<<<dim3((BB*KK) * NC), dim3(192), 0, stream>>>(xs, dtl, Bsg, dtw, dtb, A_log, Sbuf, sd);
    k_scan2<<<dim3((BB*KK*DD*NN) / 256), dim3(256), 0, stream>>>(Sbuf, sd, A_log);
    k_scan3<<<dim3((BB*KK) * NC), dim3(192), 0, stream>>>(xs, dtl, Bsg, Csg, dtw, dtb, A_log, Dsg, Sbuf);
    k_merge_ln<<<dim3((BB*LL) / 4), dim3(256), 0, stream>>>(xs, lnw, lnb, out);
}